// Round 4
// baseline (50821.680 us; speedup 1.0000x reference)
//
#include <hip/hip_runtime.h>
#include <hip/hip_bf16.h>
#include <math.h>

// ---------------- problem constants ----------------
constexpr int NND  = 2048;        // nodes
constexpr int EE   = 32768;       // edges per class graph
constexpr int ESL  = EE + NND;    // edges incl. self loops = 34816
constexpr int EMN  = 32768;       // main edge_index count
constexpr int BP   = 4096;        // train pairs
constexpr int HID  = 1024;
constexpr int SDD  = 20;
constexpr int CG   = 1044;        // HID + SE_DIM
constexpr int KC   = 7;
constexpr int NHEAD= 4;
constexpr int DH   = 261;         // CG / NHEAD

// ---------------- fp32 GEMM: C = A@B(^T) (+bias)(+relu) ----------------
// BM=128, BN in {64,128}, BK=16, 256 threads, micro-tile 8 x (BN/16).
// float4 LDS fragment reads; B-fragment split into two 4-col groups
// (tx*4 and 64+tx*4) so lane stride is 16B -> 2-way bank aliasing (free)
// instead of 4-way conflict. Batched via blockIdx.z.
// GATHER: A[m,k] = xc[gn0[m]*lda+k] * xc[gn1[m]*lda+k]  (fused pair product)
template<int BN, bool TB, bool RELU, bool GATHER>
__global__ __launch_bounds__(256)
void gemm_k(const float* __restrict__ A, int lda, long sA,
            const float* __restrict__ B, int ldb, long sB,
            float* __restrict__ C, int ldc, long sC,
            int M, int Nn, int K, const float* __restrict__ bias,
            const int* __restrict__ gn0, const int* __restrict__ gn1)
{
    constexpr int BW = BN / 16;            // 4 or 8 cols per thread
    A += (long)blockIdx.z * sA;
    B += (long)blockIdx.z * sB;
    C += (long)blockIdx.z * sC;
    __shared__ float As[16][132];
    __shared__ float Bs[16][BN + 4];
    const int m0 = blockIdx.y * 128, n0 = blockIdx.x * BN;
    const int tid = threadIdx.x;
    const int tx = tid & 15;               // N dir
    const int ty = tid >> 4;               // M dir (0..15), 8 rows each
    float acc[8][BW];
    #pragma unroll
    for (int i = 0; i < 8; ++i)
        #pragma unroll
        for (int j = 0; j < BW; ++j) acc[i][j] = 0.f;

    const int ntile = (K + 15) >> 4;
    for (int t = 0; t < ntile; ++t) {
        const int k0 = t << 4;
        #pragma unroll
        for (int l = 0; l < 8; ++l) {      // A: 128x16 = 2048 elems
            int idx = tid + l * 256;
            int kk = idx & 15, m = idx >> 4;
            float v = 0.f;
            if (m0 + m < M && k0 + kk < K) {
                if (GATHER) {
                    int p = m0 + m;
                    v = A[(long)gn0[p] * lda + k0 + kk] * A[(long)gn1[p] * lda + k0 + kk];
                } else {
                    v = A[(long)(m0 + m) * lda + k0 + kk];
                }
            }
            As[kk][m] = v;
        }
        #pragma unroll
        for (int l = 0; l < BW; ++l) {     // B: BNx16 elems
            int idx = tid + l * 256;
            float v = 0.f;
            if (TB) {
                int kk = idx & 15, n = idx >> 4;
                if (n0 + n < Nn && k0 + kk < K) v = B[(long)(n0 + n) * ldb + k0 + kk];
                Bs[kk][n] = v;
            } else {
                int n = idx % BN, kk = idx / BN;
                if (n0 + n < Nn && k0 + kk < K) v = B[(long)(k0 + kk) * ldb + n0 + n];
                Bs[kk][n] = v;
            }
        }
        __syncthreads();
        #pragma unroll
        for (int kk = 0; kk < 16; ++kk) {
            float av[8], bv[BW];
            *(float4*)&av[0] = *(const float4*)&As[kk][ty * 8];
            *(float4*)&av[4] = *(const float4*)&As[kk][ty * 8 + 4];
            *(float4*)&bv[0] = *(const float4*)&Bs[kk][tx * 4];
            if constexpr (BW == 8)
                *(float4*)&bv[4] = *(const float4*)&Bs[kk][64 + tx * 4];
            #pragma unroll
            for (int i2 = 0; i2 < 8; ++i2)
                #pragma unroll
                for (int j = 0; j < BW; ++j)
                    acc[i2][j] = fmaf(av[i2], bv[j], acc[i2][j]);
        }
        __syncthreads();
    }
    #pragma unroll
    for (int i2 = 0; i2 < 8; ++i2) {
        int m = m0 + ty * 8 + i2;
        if (m >= M) continue;
        #pragma unroll
        for (int j = 0; j < BW; ++j) {
            int nj = (BW == 8) ? ((j < 4) ? tx * 4 + j : 64 + tx * 4 + (j - 4))
                               : tx * 4 + j;
            int n = n0 + nj;
            if (n >= Nn) continue;
            float v = acc[i2][j];
            if (bias) v += bias[n];
            if (RELU) v = fmaxf(v, 0.f);
            C[(long)m * ldc + n] = v;
        }
    }
}

static inline void gemm(hipStream_t st, const float* A, int lda, long sA,
                        const float* B, int ldb, long sB,
                        float* C, int ldc, long sC,
                        int M, int Nn, int K, const float* bias,
                        bool tb, bool relu, int batch)
{
    long blocks128 = (long)((Nn + 127) / 128) * ((M + 127) / 128) * batch;
    if (blocks128 >= 256) {
        dim3 g((Nn + 127) / 128, (M + 127) / 128, batch), blk(256);
        if (tb) {
            if (relu) gemm_k<128, true , true , false><<<g, blk, 0, st>>>(A,lda,sA,B,ldb,sB,C,ldc,sC,M,Nn,K,bias,nullptr,nullptr);
            else      gemm_k<128, true , false, false><<<g, blk, 0, st>>>(A,lda,sA,B,ldb,sB,C,ldc,sC,M,Nn,K,bias,nullptr,nullptr);
        } else {
            if (relu) gemm_k<128, false, true , false><<<g, blk, 0, st>>>(A,lda,sA,B,ldb,sB,C,ldc,sC,M,Nn,K,bias,nullptr,nullptr);
            else      gemm_k<128, false, false, false><<<g, blk, 0, st>>>(A,lda,sA,B,ldb,sB,C,ldc,sC,M,Nn,K,bias,nullptr,nullptr);
        }
    } else {
        dim3 g((Nn + 63) / 64, (M + 127) / 128, batch), blk(256);
        if (tb) {
            if (relu) gemm_k<64, true , true , false><<<g, blk, 0, st>>>(A,lda,sA,B,ldb,sB,C,ldc,sC,M,Nn,K,bias,nullptr,nullptr);
            else      gemm_k<64, true , false, false><<<g, blk, 0, st>>>(A,lda,sA,B,ldb,sB,C,ldc,sC,M,Nn,K,bias,nullptr,nullptr);
        } else {
            if (relu) gemm_k<64, false, true , false><<<g, blk, 0, st>>>(A,lda,sA,B,ldb,sB,C,ldc,sC,M,Nn,K,bias,nullptr,nullptr);
            else      gemm_k<64, false, false, false><<<g, blk, 0, st>>>(A,lda,sA,B,ldb,sB,C,ldc,sC,M,Nn,K,bias,nullptr,nullptr);
        }
    }
}

// ---------------- batchnorm over rows (per-column stats), optional residual ----
__global__ __launch_bounds__(256)
void bn_k(const float* __restrict__ in, const float* __restrict__ res,
          float* __restrict__ out, const float* __restrict__ g,
          const float* __restrict__ b, int Nr, int C, int ldout)
{
    int tx = threadIdx.x & 31, ty = threadIdx.x >> 5;   // 32 cols x 8 rows
    int c = blockIdx.x * 32 + tx;
    float s = 0.f, s2 = 0.f;
    if (c < C) {
        for (int r = ty; r < Nr; r += 8) {
            float v = in[(long)r * C + c];
            if (res) v += res[(long)r * C + c];
            s += v; s2 += v * v;
        }
    }
    __shared__ float sh1[8][32], sh2[8][32];
    sh1[ty][tx] = s; sh2[ty][tx] = s2;
    __syncthreads();
    if (ty == 0) {
        for (int j = 1; j < 8; ++j) { s += sh1[j][tx]; s2 += sh2[j][tx]; }
        float mu = s / Nr;
        float var = s2 / Nr - mu * mu;
        sh1[0][tx] = mu;
        sh2[0][tx] = rsqrtf(var + 1e-5f);
    }
    __syncthreads();
    if (c < C) {
        float mu = sh1[0][tx], ri = sh2[0][tx], gg = g[c], bb = b[c];
        for (int r = ty; r < Nr; r += 8) {
            float v = in[(long)r * C + c];
            if (res) v += res[(long)r * C + c];
            out[(long)r * ldout + c] = gg * (v - mu) * ri + bb;
        }
    }
}

// ---------------- row softmax with pre-scale ----------------
__global__ __launch_bounds__(256)
void softmax_rows_k(float* __restrict__ x, int cols, float scale)
{
    float* p = x + (long)blockIdx.x * cols;
    __shared__ float red[256];
    int tid = threadIdx.x;
    float mx = -1e30f;
    for (int c = tid; c < cols; c += 256) mx = fmaxf(mx, p[c] * scale);
    red[tid] = mx; __syncthreads();
    for (int s = 128; s > 0; s >>= 1) { if (tid < s) red[tid] = fmaxf(red[tid], red[tid + s]); __syncthreads(); }
    mx = red[0]; __syncthreads();
    float sum = 0.f;
    for (int c = tid; c < cols; c += 256) { float v = expf(p[c] * scale - mx); p[c] = v; sum += v; }
    red[tid] = sum; __syncthreads();
    for (int s = 128; s > 0; s >>= 1) { if (tid < s) red[tid] += red[tid + s]; __syncthreads(); }
    float inv = 1.f / red[0];
    for (int c = tid; c < cols; c += 256) p[c] *= inv;
}

// ---------------- CSR build ----------------
__global__ void count_deg_k(const int* __restrict__ dst, int* __restrict__ deg)
{
    int e = blockIdx.x * 256 + threadIdx.x;
    if (e >= ESL) return;
    int d = (e < EE) ? dst[e] : (e - EE);
    atomicAdd(&deg[d], 1);
}

// single block, 256 threads, scans NND=2048 degrees; emits row ptr, cursor,
// and float deg-derived coefficients.
__global__ __launch_bounds__(256)
void scan_k(const int* __restrict__ deg, int* __restrict__ row, int* __restrict__ cur,
            float* __restrict__ dinv, float* __restrict__ dlin)
{
    __shared__ int part[256];
    int t = threadIdx.x;
    int base = t * 8;
    int local[8]; int s = 0;
    #pragma unroll
    for (int k = 0; k < 8; ++k) { local[k] = s; s += deg[base + k]; }
    part[t] = s; __syncthreads();
    for (int off = 1; off < 256; off <<= 1) {
        int v = (t >= off) ? part[t - off] : 0;
        __syncthreads();
        part[t] += v;
        __syncthreads();
    }
    int excl = part[t] - s;
    #pragma unroll
    for (int k = 0; k < 8; ++k) {
        int r = excl + local[k];
        row[base + k] = r; cur[base + k] = r;
        float dg = fmaxf((float)deg[base + k], 1.f);
        dinv[base + k] = rsqrtf(dg);
        dlin[base + k] = 1.f / dg;
    }
    if (t == 255) row[NND] = part[255];
}

__global__ void scatter_k(const int* __restrict__ src, const int* __restrict__ dst,
                          int* __restrict__ cur, int* __restrict__ csr_src)
{
    int e = blockIdx.x * 256 + threadIdx.x;
    if (e >= ESL) return;
    int s, d;
    if (e < EE) { s = src[e]; d = dst[e]; } else { s = d = e - EE; }
    int pos = atomicAdd(&cur[d], 1);
    csr_src[pos] = s;
}

// ---------------- CSR gather aggregation ----------------
// MODE 0: out[d] = post(d) * sum_j h[src_j]            (+bias)
// MODE 1: out[d] = sum_j dinv[src_j]*dinv[d]*h[src_j]  (+bias)   (GCN)
// MODE 2: out[d] = sum_j ew[j]*h[src_j]                (+bias)   (GAT)
template<int RMAX, int MODE>
__global__ __launch_bounds__(256)
void gather_k(const float* __restrict__ h, const int* __restrict__ row,
              const int* __restrict__ csr_src, const float* __restrict__ dinv,
              const float* __restrict__ ew, const float* __restrict__ bias,
              const float* __restrict__ post, float* __restrict__ out, int F)
{
    int d = blockIdx.x;
    int tid = threadIdx.x;
    float acc[RMAX];
    #pragma unroll
    for (int r = 0; r < RMAX; ++r) acc[r] = 0.f;
    int b0 = row[d], b1 = row[d + 1];
    float dd = (MODE == 1) ? dinv[d] : 1.f;
    for (int j = b0; j < b1; ++j) {
        int s = csr_src[j];
        float cf = 1.f;
        if (MODE == 1) cf = dinv[s] * dd;
        if (MODE == 2) cf = ew[j];
        const float* hp = h + (long)s * F;
        #pragma unroll
        for (int r = 0; r < RMAX; ++r) {
            int f = tid + r * 256;
            if (f < F) acc[r] = fmaf(hp[f], cf, acc[r]);
        }
    }
    float ps = post ? post[d] : 1.f;
    float* op = out + (long)d * F;
    #pragma unroll
    for (int r = 0; r < RMAX; ++r) {
        int f = tid + r * 256;
        if (f < F) op[f] = acc[r] * ps + (bias ? bias[f] : 0.f);
    }
}

// ---------------- GAT edge softmax (one wave per node) ----------------
__global__ __launch_bounds__(64)
void gat_alpha_k(const float* __restrict__ esrc, const float* __restrict__ edst,
                 const int* __restrict__ row, const int* __restrict__ csr_src,
                 float* __restrict__ alpha)
{
    int d = blockIdx.x, l = threadIdx.x;
    int b0 = row[d], b1 = row[d + 1];
    float ed = edst[d];
    float m = -1e30f;
    for (int j = b0 + l; j < b1; j += 64) {
        float v = esrc[csr_src[j]] + ed;
        v = (v >= 0.f) ? v : 0.2f * v;
        m = fmaxf(m, v);
    }
    #pragma unroll
    for (int off = 32; off; off >>= 1) m = fmaxf(m, __shfl_xor(m, off));
    float sum = 0.f;
    for (int j = b0 + l; j < b1; j += 64) {
        float v = esrc[csr_src[j]] + ed;
        v = (v >= 0.f) ? v : 0.2f * v;
        float ex = expf(v - m);
        alpha[j] = ex; sum += ex;
    }
    #pragma unroll
    for (int off = 32; off; off >>= 1) sum += __shfl_xor(sum, off);
    float inv = 1.f / sum;
    for (int j = b0 + l; j < b1; j += 64) alpha[j] *= inv;
}

// ---------------- small elementwise kernels ----------------
__global__ void concat_t_k(const float* __restrict__ x, const float* __restrict__ se,
                           float* __restrict__ t)
{
    long idx = (long)blockIdx.x * 256 + threadIdx.x;
    long total = (long)NND * CG;
    if (idx >= total) return;
    int r = (int)(idx / CG), c = (int)(idx % CG);
    t[idx] = (c < HID) ? x[(long)r * HID + c] : se[(long)r * SDD + (c - HID)];
}

__global__ void copy_x_xc_k(const float* __restrict__ x, float* __restrict__ xc)
{
    long idx = (long)blockIdx.x * 256 + threadIdx.x;
    long total = (long)NND * HID;
    if (idx >= total) return;
    int r = (int)(idx / HID), c = (int)(idx % HID);
    xc[(long)r * 8192 + c] = x[idx];
}

__global__ void add_k(float* __restrict__ a, const float* __restrict__ b, long total)
{
    long idx = (long)blockIdx.x * 256 + threadIdx.x;
    if (idx >= total) return;
    a[idx] += b[idx];
}

__global__ void avg3_k(const float* __restrict__ a, const float* __restrict__ b,
                       const float* __restrict__ c, float* __restrict__ o, long total)
{
    long idx = (long)blockIdx.x * 256 + threadIdx.x;
    if (idx >= total) return;
    o[idx] = (a[idx] + b[idx] + c[idx]) * (1.f / 3.f);
}

// per-node dot products with attention vectors
__global__ __launch_bounds__(256)
void gat_dots_k(const float* __restrict__ h, const float* __restrict__ asrc,
                const float* __restrict__ adst, float* __restrict__ esrc,
                float* __restrict__ edst)
{
    int n = blockIdx.x, tid = threadIdx.x;
    float s1 = 0.f, s2 = 0.f;
    for (int f = tid; f < HID; f += 256) {
        float v = h[(long)n * HID + f];
        s1 += v * asrc[f]; s2 += v * adst[f];
    }
    __shared__ float r1[256], r2[256];
    r1[tid] = s1; r2[tid] = s2; __syncthreads();
    for (int s = 128; s > 0; s >>= 1) {
        if (tid < s) { r1[tid] += r1[tid + s]; r2[tid] += r2[tid + s]; }
        __syncthreads();
    }
    if (tid == 0) { esrc[n] = r1[0]; edst[n] = r2[0]; }
}

// pair node-index precompute: n0[p]=eidx[teid[p]], n1[p]=eidx[EMN+teid[p]]
__global__ void pair_idx_k(const int* __restrict__ eidx, const int* __restrict__ teid,
                           int* __restrict__ n0, int* __restrict__ n1)
{
    int p = blockIdx.x * 256 + threadIdx.x;
    if (p >= BP) return;
    int t = teid[p];
    n0[p] = eidx[t];
    n1[p] = eidx[EMN + t];
}

// ---------------- launch ----------------
static inline int cdiv(long a, int b) { return (int)((a + b - 1) / b); }

extern "C" void kernel_launch(void* const* d_in, const int* in_sizes, int n_in,
                              void* d_out, int out_size, void* d_ws, size_t ws_size,
                              hipStream_t stream)
{
    const float* x    = (const float*)d_in[0];
    const float* se   = (const float*)d_in[1];
    const int*   sev  = (const int*)  d_in[2];
    const int*   eidx = (const int*)  d_in[3];
    const int*   teid = (const int*)  d_in[4];
    const float* gpsW = (const float*)d_in[5];
    const float* gpsB = (const float*)d_in[6];
    const float* aiW  = (const float*)d_in[7];
    const float* aiB  = (const float*)d_in[8];
    const float* aoW  = (const float*)d_in[9];
    const float* aoB  = (const float*)d_in[10];
    const float* bn1g = (const float*)d_in[11];
    const float* bn1b = (const float*)d_in[12];
    const float* bn2g = (const float*)d_in[13];
    const float* bn2b = (const float*)d_in[14];
    const float* bn3g = (const float*)d_in[15];
    const float* bn3b = (const float*)d_in[16];
    const float* mW1  = (const float*)d_in[17];
    const float* mb1  = (const float*)d_in[18];
    const float* mW2  = (const float*)d_in[19];
    const float* mb2  = (const float*)d_in[20];
    const float* slW  = (const float*)d_in[21];
    const float* slB  = (const float*)d_in[22];
    const float* gatW = (const float*)d_in[23];
    const float* gatAs= (const float*)d_in[24];
    const float* gatAd= (const float*)d_in[25];
    const float* gatB = (const float*)d_in[26];
    const float* subW = (const float*)d_in[27];
    const float* subB = (const float*)d_in[28];
    const float* gcnW = (const float*)d_in[29];
    const float* gcnB = (const float*)d_in[30];
    const float* bnfg = (const float*)d_in[31];
    const float* bnfb = (const float*)d_in[32];
    const float* cW0 = (const float*)d_in[33]; const float* cb0 = (const float*)d_in[34];
    const float* cW1 = (const float*)d_in[35]; const float* cb1 = (const float*)d_in[36];
    const float* cW2 = (const float*)d_in[37]; const float* cb2 = (const float*)d_in[38];
    const float* cW3 = (const float*)d_in[39]; const float* cb3 = (const float*)d_in[40];
    const float* cW4 = (const float*)d_in[41]; const float* cb4 = (const float*)d_in[42];
    const float* cW5 = (const float*)d_in[43]; const float* cb5 = (const float*)d_in[44];
    float* out = (float*)d_out;
    float* w   = (float*)d_ws;

    // ---- workspace layout (floats), peak ~195 MiB ----
    // Aliasing: scores (o_sc, 16.8M) are dead after the att@v GEMM; the MLP
    // intermediate (o_mid, 4.3M) and the GAT-phase u0..u4 (10.5M) live inside
    // the score region in disjoint sub-ranges.
    const size_t o_xc  = 0;                          // 2048*8192 (persistent)
    const size_t region= (size_t)NND * 8192;
    const size_t o_t   = region;
    const size_t o_ha  = o_t  + (size_t)NND * CG;
    const size_t o_hb  = o_ha + (size_t)NND * CG;
    const size_t o_hc  = o_hb + (size_t)NND * CG;
    const size_t o_qkv = o_hc + (size_t)NND * CG;    // 2048*3132
    const size_t o_sc  = o_qkv+ (size_t)NND * 3*CG;  // 4*2048*2048 scores
    const size_t o_mid = o_sc;                       // alias: 2048*2088 (MLP mid)
    const size_t o_u0  = o_sc + (size_t)NND * 2*CG;  // alias: 5 x 2048*1024
    const size_t o_u1  = o_u0 + (size_t)NND * HID;
    const size_t o_u2  = o_u1 + (size_t)NND * HID;
    const size_t o_u3  = o_u2 + (size_t)NND * HID;
    const size_t o_u4  = o_u3 + (size_t)NND * HID;
    const size_t o_sm  = o_sc + (size_t)NHEAD * NND * NND;   // past score region
    const size_t o_div = o_sm;                       // NND
    const size_t o_dli = o_div + NND;
    const size_t o_es  = o_dli + NND;
    const size_t o_ed  = o_es + NND;
    const size_t o_al  = o_ed + NND;                 // ESL (edge alphas, CSR order)
    const size_t o_int = o_al + ESL;
    int* ideg = (int*)(w + o_int);                   // NND
    int* irow = ideg + NND;                          // NND+1
    int* icur = irow + NND + 1;                      // NND
    int* icsr = icur + NND;                          // ESL
    int* pn0  = icsr + ESL;                          // BP
    int* pn1  = pn0 + BP;                            // BP
    // classifier ping-pong reuses [region ...) (all per-class buffers dead):
    const size_t o_c1  = region;                     // 4096*4096
    const size_t o_c2  = region + (size_t)BP * 4096; // 4096*2048

    const float scale = 1.f / sqrtf((float)DH);

    // xc[:, :1024] = x
    copy_x_xc_k<<<cdiv((long)NND * HID, 256), 256, 0, stream>>>(x, w + o_xc);

    for (int i = 0; i < KC; ++i) {
        const int* srcp = sev + (long)i * 2 * EE;
        const int* dstp = srcp + EE;
        float* t  = w + o_t;
        float* hA = w + o_ha;
        float* hB = w + o_hb;
        float* hC = w + o_hc;

        // t = concat(x, se[i])
        concat_t_k<<<cdiv((long)NND * CG, 256), 256, 0, stream>>>(x, se + (long)i * NND * SDD, t);

        // ---- CSR build (shared by all 5 aggregations of this class) ----
        hipMemsetAsync(ideg, 0, NND * sizeof(int), stream);
        count_deg_k<<<cdiv(ESL, 256), 256, 0, stream>>>(dstp, ideg);
        scan_k<<<1, 256, 0, stream>>>(ideg, irow, icur, w + o_div, w + o_dli);
        scatter_k<<<cdiv(ESL, 256), 256, 0, stream>>>(srcp, dstp, icur, icsr);

        // ---- GCN1: hB = bn1( gcn(t) + t ) ----
        gemm(stream, t, CG, 0, gpsW + (long)i * CG * CG, CG, 0, hA, CG, 0,
             NND, CG, CG, nullptr, false, false, 1);
        gather_k<5, 1><<<NND, 256, 0, stream>>>(hA, irow, icsr, w + o_div, nullptr,
                                                gpsB + (long)i * CG, nullptr, hB, CG);
        bn_k<<<cdiv(CG, 32), 256, 0, stream>>>(hB, t, hB, bn1g + (long)i * CG, bn1b + (long)i * CG, NND, CG, CG);

        // ---- MHA ----
        gemm(stream, t, CG, 0, aiW + (long)i * 3 * CG * CG, CG, 0, w + o_qkv, 3 * CG, 0,
             NND, 3 * CG, CG, aiB + (long)i * 3 * CG, true, false, 1);
        gemm(stream, w + o_qkv, 3 * CG, DH, w + o_qkv + CG, 3 * CG, DH,
             w + o_sc, NND, (long)NND * NND, NND, NND, DH, nullptr, true, false, NHEAD);
        softmax_rows_k<<<NHEAD * NND, 256, 0, stream>>>(w + o_sc, NND, scale);
        gemm(stream, w + o_sc, NND, (long)NND * NND, w + o_qkv + 2 * CG, 3 * CG, DH,
             hA, CG, DH, NND, DH, NND, nullptr, false, false, NHEAD);
        gemm(stream, hA, CG, 0, aoW + (long)i * CG * CG, CG, 0, hC, CG, 0,
             NND, CG, CG, aoB + (long)i * CG, true, false, 1);
        bn_k<<<cdiv(CG, 32), 256, 0, stream>>>(hC, t, hC, bn2g + (long)i * CG, bn2b + (long)i * CG, NND, CG, CG);

        // h = h_local + h_attn  -> hB
        add_k<<<cdiv((long)NND * CG, 256), 256, 0, stream>>>(hB, hC, (long)NND * CG);

        // ---- MLP + bn3 ----
        gemm(stream, hB, CG, 0, mW1 + (long)i * CG * 2 * CG, 2 * CG, 0, w + o_mid, 2 * CG, 0,
             NND, 2 * CG, CG, mb1 + (long)i * 2 * CG, false, true, 1);
        gemm(stream, w + o_mid, 2 * CG, 0, mW2 + (long)i * 2 * CG * CG, CG, 0, hC, CG, 0,
             NND, CG, 2 * CG, mb2 + (long)i * CG, false, false, 1);
        bn_k<<<cdiv(CG, 32), 256, 0, stream>>>(hC, hB, hB, bn3g + (long)i * CG, bn3b + (long)i * CG, NND, CG, CG);

        // ---- se_lin: u0 = h @ W + b ----
        gemm(stream, hB, CG, 0, slW + (long)i * CG * HID, HID, 0, w + o_u0, HID, 0,
             NND, HID, CG, slB + (long)i * HID, false, false, 1);

        // ---- GAT ----
        gemm(stream, w + o_u0, HID, 0, gatW + (long)i * HID * HID, HID, 0, w + o_u1, HID, 0,
             NND, HID, HID, nullptr, false, false, 1);
        gat_dots_k<<<NND, 256, 0, stream>>>(w + o_u1, gatAs + (long)i * HID, gatAd + (long)i * HID,
                                            w + o_es, w + o_ed);
        gat_alpha_k<<<NND, 64, 0, stream>>>(w + o_es, w + o_ed, irow, icsr, w + o_al);
        gather_k<4, 2><<<NND, 256, 0, stream>>>(w + o_u1, irow, icsr, nullptr, w + o_al,
                                                gatB + (long)i * HID, nullptr, w + o_u2, HID);

        // ---- h1 = mean-agg(t) ; h2 = mean-agg(h1) ----
        gather_k<4, 0><<<NND, 256, 0, stream>>>(w + o_u2, irow, icsr, nullptr, nullptr,
                                                nullptr, w + o_dli, w + o_u3, HID);
        gather_k<4, 0><<<NND, 256, 0, stream>>>(w + o_u3, irow, icsr, nullptr, nullptr,
                                                nullptr, w + o_dli, w + o_u4, HID);

        // t_sub = relu(((t+h1+h2)/3) @ subW + b) -> u1
        avg3_k<<<cdiv((long)NND * HID, 256), 256, 0, stream>>>(w + o_u2, w + o_u3, w + o_u4, w + o_u0, (long)NND * HID);
        gemm(stream, w + o_u0, HID, 0, subW + (long)i * HID * HID, HID, 0, w + o_u1, HID, 0,
             NND, HID, HID, subB + (long)i * HID, false, true, 1);

        // ---- GCN2 on u2 ----
        gemm(stream, w + o_u2, HID, 0, gcnW + (long)i * HID * HID, HID, 0, w + o_u4, HID, 0,
             NND, HID, HID, nullptr, false, false, 1);
        gather_k<4, 1><<<NND, 256, 0, stream>>>(w + o_u4, irow, icsr, w + o_div, nullptr,
                                                gcnB + (long)i * HID, nullptr, w + o_u3, HID);

        // t = bnf(gcn2 + t_sub) -> xc slice
        bn_k<<<cdiv(HID, 32), 256, 0, stream>>>(w + o_u3, w + o_u1, w + o_xc + (size_t)HID * (i + 1),
                                                bnfg + (long)i * HID, bnfb + (long)i * HID, NND, HID, 8192);
    }

    // ---- classifier: L0 fuses the pair product gather into the A-stage ----
    pair_idx_k<<<cdiv(BP, 256), 256, 0, stream>>>(eidx, teid, pn0, pn1);
    {
        dim3 g((4096 + 127) / 128, (BP + 127) / 128, 1), blk(256);
        gemm_k<128, false, false, true><<<g, blk, 0, stream>>>(
            w + o_xc, 8192, 0, cW0, 4096, 0, w + o_c1, 4096, 0,
            BP, 4096, 8192, cb0, pn0, pn1);
    }
    gemm(stream, w + o_c1, 4096, 0, cW1, 2048, 0, w + o_c2, 2048, 0, BP, 2048, 4096, cb1, false, false, 1);
    gemm(stream, w + o_c2, 2048, 0, cW2, 1024, 0, w + o_c1, 1024, 0, BP, 1024, 2048, cb2, false, false, 1);
    gemm(stream, w + o_c1, 1024, 0, cW3,  512, 0, w + o_c2,  512, 0, BP,  512, 1024, cb3, false, false, 1);
    gemm(stream, w + o_c2,  512, 0, cW4,  256, 0, w + o_c1,  256, 0, BP,  256,  512, cb4, false, false, 1);
    gemm(stream, w + o_c1,  256, 0, cW5,    7, 0, out,         7, 0, BP,    7,  256, cb5, false, false, 1);
}

// Round 6
// 25914.948 us; speedup vs baseline: 1.9611x; 1.9611x over previous
//
#include <hip/hip_runtime.h>
#include <hip/hip_bf16.h>
#include <math.h>

// ---------------- problem constants ----------------
constexpr int NND  = 2048;        // nodes
constexpr int EE   = 32768;       // edges per class graph
constexpr int ESL  = EE + NND;    // edges incl. self loops = 34816
constexpr int EMN  = 32768;       // main edge_index count
constexpr int BP   = 4096;        // train pairs
constexpr int HID  = 1024;
constexpr int SDD  = 20;
constexpr int CG   = 1044;        // HID + SE_DIM
constexpr int KC   = 7;
constexpr int NHEAD= 4;
constexpr int DH   = 261;         // CG / NHEAD

typedef __attribute__((ext_vector_type(8))) short short8v;
typedef __attribute__((ext_vector_type(4))) float f32x4;
typedef __attribute__((ext_vector_type(4))) unsigned short ushort4v;

// ================= split-bf16 MFMA GEMM =================
// C = A @ B(^T) (+bias)(+relu), fp32 in/out, internally A,B split into
// bf16 hi+lo; 3 MFMA passes (hi*hi + hi*lo + lo*hi) => ~2^-16 rel error.
// Tile 128x128, BK=32, 256 threads = 4 waves, each wave a 64x64 sub-tile
// of 4x4 mfma_f32_16x16x32_bf16 fragments. M must be a multiple of 128.
// Fragment layouts (gfx950 16x16x32): A lane l -> row=l&15, k=(l>>4)*8+j;
// B lane l -> col=l&15, k=(l>>4)*8+j; C/D col=lane&15, row=(lane>>4)*4+r
// (m89-verified). LDS: [row][32k] bf16 rows of 64B, 16B-chunk XOR swizzle
// chunk ^= (row>>1)&3 applied identically on write and read (bijective per
// 8-row stripe).
// GATHER: A[m,k] = A[gn0[m]*lda+k] * A[gn1[m]*lda+k] (fused pair product).
template<bool TB, bool RELU, bool GATHER, int PASSES>
__global__ __launch_bounds__(256)
void gemm_mfma_k(const float* __restrict__ A, int lda, long sA,
                 const float* __restrict__ B, int ldb, long sB,
                 float* __restrict__ C, int ldc, long sC,
                 int M, int Nn, int K, const float* __restrict__ bias,
                 const int* __restrict__ gn0, const int* __restrict__ gn1)
{
    A += (long)blockIdx.z * sA;
    B += (long)blockIdx.z * sB;
    C += (long)blockIdx.z * sC;
    __shared__ unsigned short sAh[128 * 32], sAl[128 * 32];
    __shared__ unsigned short sBh[128 * 32], sBl[128 * 32];

    const int tid  = threadIdx.x;
    const int lane = tid & 63, wid = tid >> 6;
    const int wr = wid >> 1, wc = wid & 1;          // 2x2 wave grid
    const int m0 = blockIdx.y * 128, n0 = blockIdx.x * 128;

    f32x4 acc[4][4];
    #pragma unroll
    for (int i = 0; i < 4; ++i)
        #pragma unroll
        for (int j = 0; j < 4; ++j)
            #pragma unroll
            for (int r = 0; r < 4; ++r) acc[i][j][r] = 0.f;

    // staging roles
    const int ar  = tid >> 1;              // row (A) / row n (B when TB)
    const int akh = (tid & 1) << 4;        // k-half: 0/16
    const int bkq = (tid >> 5) << 2;       // k quad (TB=false): 0..28
    const int bnb = (tid & 31) << 2;       // n base (TB=false): 0..124

    long gA0 = 0, gA1 = 0, aBase = 0;
    if (GATHER) {
        gA0 = (long)gn0[m0 + ar] * lda;
        gA1 = (long)gn1[m0 + ar] * lda;
    } else {
        aBase = (long)(m0 + ar) * lda;
    }
    const long bBaseT = TB ? (long)(n0 + ar) * ldb : 0;
    const bool bRowOkT = TB ? (n0 + ar) < Nn : false;

    const int nk = (K + 31) >> 5;
    for (int t = 0; t < nk; ++t) {
        const int k0 = t << 5;
        // ---- stage A (hi/lo) ----
        {
            float v[16];
            #pragma unroll
            for (int j = 0; j < 16; ++j) {
                int kk = k0 + akh + j;
                float x = 0.f;
                if (kk < K) {
                    if (GATHER) x = A[gA0 + kk] * A[gA1 + kk];
                    else        x = A[aBase + kk];
                }
                v[j] = x;
            }
            #pragma unroll
            for (int c2 = 0; c2 < 2; ++c2) {
                int chunk = (akh >> 3) + c2;
                int off = ar * 32 + ((chunk ^ ((ar >> 1) & 3)) << 3);
                short8v hv, lv;
                #pragma unroll
                for (int j = 0; j < 8; ++j) {
                    float x = v[c2 * 8 + j];
                    unsigned hb = __float_as_uint(x) & 0xFFFF0000u;
                    hv[j] = (short)(hb >> 16);
                    float lo = x - __uint_as_float(hb);
                    lv[j] = (short)(__float_as_uint(lo) >> 16);
                }
                *(short8v*)&sAh[off] = hv;
                *(short8v*)&sAl[off] = lv;
            }
        }
        // ---- stage B (hi/lo) ----
        if (TB) {
            float v[16];
            #pragma unroll
            for (int j = 0; j < 16; ++j) {
                int kk = k0 + akh + j;
                v[j] = (bRowOkT && kk < K) ? B[bBaseT + kk] : 0.f;
            }
            #pragma unroll
            for (int c2 = 0; c2 < 2; ++c2) {
                int chunk = (akh >> 3) + c2;
                int off = ar * 32 + ((chunk ^ ((ar >> 1) & 3)) << 3);
                short8v hv, lv;
                #pragma unroll
                for (int j = 0; j < 8; ++j) {
                    float x = v[c2 * 8 + j];
                    unsigned hb = __float_as_uint(x) & 0xFFFF0000u;
                    hv[j] = (short)(hb >> 16);
                    float lo = x - __uint_as_float(hb);
                    lv[j] = (short)(__float_as_uint(lo) >> 16);
                }
                *(short8v*)&sBh[off] = hv;
                *(short8v*)&sBl[off] = lv;
            }
        } else {
            float vv[4][4];
            #pragma unroll
            for (int j = 0; j < 4; ++j) {
                int kk = k0 + bkq + j;
                const float* bp = B + (long)kk * ldb;
                #pragma unroll
                for (int i = 0; i < 4; ++i) {
                    int nn = n0 + bnb + i;
                    vv[j][i] = (kk < K && nn < Nn) ? bp[nn] : 0.f;
                }
            }
            #pragma unroll
            for (int i = 0; i < 4; ++i) {
                int n = bnb + i;
                int off = n * 32 + (((bkq >> 3) ^ ((n >> 1) & 3)) << 3) + (bkq & 7);
                ushort4v hv, lv;
                #pragma unroll
                for (int j = 0; j < 4; ++j) {
                    float x = vv[j][i];
                    unsigned hb = __float_as_uint(x) & 0xFFFF0000u;
                    hv[j] = (unsigned short)(hb >> 16);
                    float lo = x - __uint_as_float(hb);
                    lv[j] = (unsigned short)(__float_as_uint(lo) >> 16);
                }
                *(ushort4v*)&sBh[off] = hv;
                *(ushort4v*)&sBl[off] = lv;
            }
        }
        __syncthreads();
        // ---- fragments + MFMA ----
        const int la = lane & 15, lb = lane >> 4;
        short8v aH[4], aL[4];
        #pragma unroll
        for (int i = 0; i < 4; ++i) {
            int row = wr * 64 + i * 16 + la;
            int off = row * 32 + ((lb ^ ((row >> 1) & 3)) << 3);
            aH[i] = *(const short8v*)&sAh[off];
            aL[i] = *(const short8v*)&sAl[off];
        }
        #pragma unroll
        for (int jn = 0; jn < 4; ++jn) {
            int col = wc * 64 + jn * 16 + la;
            int off = col * 32 + ((lb ^ ((col >> 1) & 3)) << 3);
            short8v bH = *(const short8v*)&sBh[off];
            short8v bL = *(const short8v*)&sBl[off];
            #pragma unroll
            for (int i = 0; i < 4; ++i) {
                acc[i][jn] = __builtin_amdgcn_mfma_f32_16x16x32_bf16(aH[i], bH, acc[i][jn], 0, 0, 0);
                if (PASSES >= 2)
                    acc[i][jn] = __builtin_amdgcn_mfma_f32_16x16x32_bf16(aH[i], bL, acc[i][jn], 0, 0, 0);
                if (PASSES >= 3)
                    acc[i][jn] = __builtin_amdgcn_mfma_f32_16x16x32_bf16(aL[i], bH, acc[i][jn], 0, 0, 0);
            }
        }
        __syncthreads();
    }
    // ---- epilogue: C/D layout col=lane&15, row=(lane>>4)*4+r ----
    const int la = lane & 15, lb = lane >> 4;
    #pragma unroll
    for (int i = 0; i < 4; ++i) {
        int rg = m0 + wr * 64 + i * 16 + lb * 4;
        #pragma unroll
        for (int jn = 0; jn < 4; ++jn) {
            int cg = n0 + wc * 64 + jn * 16 + la;
            if (cg >= Nn) continue;
            float bb = bias ? bias[cg] : 0.f;
            #pragma unroll
            for (int r = 0; r < 4; ++r) {
                float x = acc[i][jn][r] + bb;
                if (RELU) x = fmaxf(x, 0.f);
                C[(long)(rg + r) * ldc + cg] = x;
            }
        }
    }
}

// ---------------- fp32 GEMM fallback (small N) ----------------
template<int BN, bool TB, bool RELU>
__global__ __launch_bounds__(256)
void gemm_k(const float* __restrict__ A, int lda, long sA,
            const float* __restrict__ B, int ldb, long sB,
            float* __restrict__ C, int ldc, long sC,
            int M, int Nn, int K, const float* __restrict__ bias)
{
    constexpr int BW = BN / 16;
    A += (long)blockIdx.z * sA;
    B += (long)blockIdx.z * sB;
    C += (long)blockIdx.z * sC;
    __shared__ float As[16][132];
    __shared__ float Bs[16][BN + 4];
    const int m0 = blockIdx.y * 128, n0 = blockIdx.x * BN;
    const int tid = threadIdx.x;
    const int tx = tid & 15, ty = tid >> 4;
    float acc[8][BW];
    #pragma unroll
    for (int i = 0; i < 8; ++i)
        #pragma unroll
        for (int j = 0; j < BW; ++j) acc[i][j] = 0.f;

    const int ntile = (K + 15) >> 4;
    for (int t = 0; t < ntile; ++t) {
        const int k0 = t << 4;
        #pragma unroll
        for (int l = 0; l < 8; ++l) {
            int idx = tid + l * 256;
            int kk = idx & 15, m = idx >> 4;
            float v = 0.f;
            if (m0 + m < M && k0 + kk < K) v = A[(long)(m0 + m) * lda + k0 + kk];
            As[kk][m] = v;
        }
        #pragma unroll
        for (int l = 0; l < BW; ++l) {
            int idx = tid + l * 256;
            float v = 0.f;
            if (TB) {
                int kk = idx & 15, n = idx >> 4;
                if (n0 + n < Nn && k0 + kk < K) v = B[(long)(n0 + n) * ldb + k0 + kk];
                Bs[kk][n] = v;
            } else {
                int n = idx % BN, kk = idx / BN;
                if (n0 + n < Nn && k0 + kk < K) v = B[(long)(k0 + kk) * ldb + n0 + n];
                Bs[kk][n] = v;
            }
        }
        __syncthreads();
        #pragma unroll
        for (int kk = 0; kk < 16; ++kk) {
            float av[8], bv[BW];
            *(float4*)&av[0] = *(const float4*)&As[kk][ty * 8];
            *(float4*)&av[4] = *(const float4*)&As[kk][ty * 8 + 4];
            *(float4*)&bv[0] = *(const float4*)&Bs[kk][tx * 4];
            if constexpr (BW == 8)
                *(float4*)&bv[4] = *(const float4*)&Bs[kk][64 + tx * 4];
            #pragma unroll
            for (int i2 = 0; i2 < 8; ++i2)
                #pragma unroll
                for (int j = 0; j < BW; ++j)
                    acc[i2][j] = fmaf(av[i2], bv[j], acc[i2][j]);
        }
        __syncthreads();
    }
    #pragma unroll
    for (int i2 = 0; i2 < 8; ++i2) {
        int m = m0 + ty * 8 + i2;
        if (m >= M) continue;
        #pragma unroll
        for (int j = 0; j < BW; ++j) {
            int nj = (BW == 8) ? ((j < 4) ? tx * 4 + j : 64 + tx * 4 + (j - 4))
                               : tx * 4 + j;
            int n = n0 + nj;
            if (n >= Nn) continue;
            float v = acc[i2][j];
            if (bias) v += bias[n];
            if (RELU) v = fmaxf(v, 0.f);
            C[(long)m * ldc + n] = v;
        }
    }
}

static inline void gemm(hipStream_t st, const float* A, int lda, long sA,
                        const float* B, int ldb, long sB,
                        float* C, int ldc, long sC,
                        int M, int Nn, int K, const float* bias,
                        bool tb, bool relu, int batch)
{
    if (Nn >= 64 && (M & 127) == 0) {   // split-bf16 MFMA path
        dim3 g((Nn + 127) / 128, M / 128, batch), blk(256);
        if (tb) {
            if (relu) gemm_mfma_k<true , true , false, 3><<<g, blk, 0, st>>>(A,lda,sA,B,ldb,sB,C,ldc,sC,M,Nn,K,bias,nullptr,nullptr);
            else      gemm_mfma_k<true , false, false, 3><<<g, blk, 0, st>>>(A,lda,sA,B,ldb,sB,C,ldc,sC,M,Nn,K,bias,nullptr,nullptr);
        } else {
            if (relu) gemm_mfma_k<false, true , false, 3><<<g, blk, 0, st>>>(A,lda,sA,B,ldb,sB,C,ldc,sC,M,Nn,K,bias,nullptr,nullptr);
            else      gemm_mfma_k<false, false, false, 3><<<g, blk, 0, st>>>(A,lda,sA,B,ldb,sB,C,ldc,sC,M,Nn,K,bias,nullptr,nullptr);
        }
    } else {                            // fp32 fallback (tiny N)
        dim3 g((Nn + 63) / 64, (M + 127) / 128, batch), blk(256);
        if (tb) {
            if (relu) gemm_k<64, true , true ><<<g, blk, 0, st>>>(A,lda,sA,B,ldb,sB,C,ldc,sC,M,Nn,K,bias);
            else      gemm_k<64, true , false><<<g, blk, 0, st>>>(A,lda,sA,B,ldb,sB,C,ldc,sC,M,Nn,K,bias);
        } else {
            if (relu) gemm_k<64, false, true ><<<g, blk, 0, st>>>(A,lda,sA,B,ldb,sB,C,ldc,sC,M,Nn,K,bias);
            else      gemm_k<64, false, false><<<g, blk, 0, st>>>(A,lda,sA,B,ldb,sB,C,ldc,sC,M,Nn,K,bias);
        }
    }
}

// ---------------- batchnorm over rows (per-column stats), optional residual ----
__global__ __launch_bounds__(256)
void bn_k(const float* __restrict__ in, const float* __restrict__ res,
          float* __restrict__ out, const float* __restrict__ g,
          const float* __restrict__ b, int Nr, int C, int ldout)
{
    int tx = threadIdx.x & 31, ty = threadIdx.x >> 5;   // 32 cols x 8 rows
    int c = blockIdx.x * 32 + tx;
    float s = 0.f, s2 = 0.f;
    if (c < C) {
        for (int r = ty; r < Nr; r += 8) {
            float v = in[(long)r * C + c];
            if (res) v += res[(long)r * C + c];
            s += v; s2 += v * v;
        }
    }
    __shared__ float sh1[8][32], sh2[8][32];
    sh1[ty][tx] = s; sh2[ty][tx] = s2;
    __syncthreads();
    if (ty == 0) {
        for (int j = 1; j < 8; ++j) { s += sh1[j][tx]; s2 += sh2[j][tx]; }
        float mu = s / Nr;
        float var = s2 / Nr - mu * mu;
        sh1[0][tx] = mu;
        sh2[0][tx] = rsqrtf(var + 1e-5f);
    }
    __syncthreads();
    if (c < C) {
        float mu = sh1[0][tx], ri = sh2[0][tx], gg = g[c], bb = b[c];
        for (int r = ty; r < Nr; r += 8) {
            float v = in[(long)r * C + c];
            if (res) v += res[(long)r * C + c];
            out[(long)r * ldout + c] = gg * (v - mu) * ri + bb;
        }
    }
}

// ---------------- row softmax with pre-scale ----------------
__global__ __launch_bounds__(256)
void softmax_rows_k(float* __restrict__ x, int cols, float scale)
{
    float* p = x + (long)blockIdx.x * cols;
    __shared__ float red[256];
    int tid = threadIdx.x;
    float mx = -1e30f;
    for (int c = tid; c < cols; c += 256) mx = fmaxf(mx, p[c] * scale);
    red[tid] = mx; __syncthreads();
    for (int s = 128; s > 0; s >>= 1) { if (tid < s) red[tid] = fmaxf(red[tid], red[tid + s]); __syncthreads(); }
    mx = red[0]; __syncthreads();
    float sum = 0.f;
    for (int c = tid; c < cols; c += 256) { float v = expf(p[c] * scale - mx); p[c] = v; sum += v; }
    red[tid] = sum; __syncthreads();
    for (int s = 128; s > 0; s >>= 1) { if (tid < s) red[tid] += red[tid + s]; __syncthreads(); }
    float inv = 1.f / red[0];
    for (int c = tid; c < cols; c += 256) p[c] *= inv;
}

// ---------------- CSR build ----------------
__global__ void count_deg_k(const int* __restrict__ dst, int* __restrict__ deg)
{
    int e = blockIdx.x * 256 + threadIdx.x;
    if (e >= ESL) return;
    int d = (e < EE) ? dst[e] : (e - EE);
    atomicAdd(&deg[d], 1);
}

__global__ __launch_bounds__(256)
void scan_k(const int* __restrict__ deg, int* __restrict__ row, int* __restrict__ cur,
            float* __restrict__ dinv, float* __restrict__ dlin)
{
    __shared__ int part[256];
    int t = threadIdx.x;
    int base = t * 8;
    int local[8]; int s = 0;
    #pragma unroll
    for (int k = 0; k < 8; ++k) { local[k] = s; s += deg[base + k]; }
    part[t] = s; __syncthreads();
    for (int off = 1; off < 256; off <<= 1) {
        int v = (t >= off) ? part[t - off] : 0;
        __syncthreads();
        part[t] += v;
        __syncthreads();
    }
    int excl = part[t] - s;
    #pragma unroll
    for (int k = 0; k < 8; ++k) {
        int r = excl + local[k];
        row[base + k] = r; cur[base + k] = r;
        float dg = fmaxf((float)deg[base + k], 1.f);
        dinv[base + k] = rsqrtf(dg);
        dlin[base + k] = 1.f / dg;
    }
    if (t == 255) row[NND] = part[255];
}

__global__ void scatter_k(const int* __restrict__ src, const int* __restrict__ dst,
                          int* __restrict__ cur, int* __restrict__ csr_src)
{
    int e = blockIdx.x * 256 + threadIdx.x;
    if (e >= ESL) return;
    int s, d;
    if (e < EE) { s = src[e]; d = dst[e]; } else { s = d = e - EE; }
    int pos = atomicAdd(&cur[d], 1);
    csr_src[pos] = s;
}

// ---------------- CSR gather aggregation ----------------
template<int RMAX, int MODE>
__global__ __launch_bounds__(256)
void gather_k(const float* __restrict__ h, const int* __restrict__ row,
              const int* __restrict__ csr_src, const float* __restrict__ dinv,
              const float* __restrict__ ew, const float* __restrict__ bias,
              const float* __restrict__ post, float* __restrict__ out, int F)
{
    int d = blockIdx.x;
    int tid = threadIdx.x;
    float acc[RMAX];
    #pragma unroll
    for (int r = 0; r < RMAX; ++r) acc[r] = 0.f;
    int b0 = row[d], b1 = row[d + 1];
    float dd = (MODE == 1) ? dinv[d] : 1.f;
    for (int j = b0; j < b1; ++j) {
        int s = csr_src[j];
        float cf = 1.f;
        if (MODE == 1) cf = dinv[s] * dd;
        if (MODE == 2) cf = ew[j];
        const float* hp = h + (long)s * F;
        #pragma unroll
        for (int r = 0; r < RMAX; ++r) {
            int f = tid + r * 256;
            if (f < F) acc[r] = fmaf(hp[f], cf, acc[r]);
        }
    }
    float ps = post ? post[d] : 1.f;
    float* op = out + (long)d * F;
    #pragma unroll
    for (int r = 0; r < RMAX; ++r) {
        int f = tid + r * 256;
        if (f < F) op[f] = acc[r] * ps + (bias ? bias[f] : 0.f);
    }
}

// ---------------- GAT edge softmax (one wave per node) ----------------
__global__ __launch_bounds__(64)
void gat_alpha_k(const float* __restrict__ esrc, const float* __restrict__ edst,
                 const int* __restrict__ row, const int* __restrict__ csr_src,
                 float* __restrict__ alpha)
{
    int d = blockIdx.x, l = threadIdx.x;
    int b0 = row[d], b1 = row[d + 1];
    float ed = edst[d];
    float m = -1e30f;
    for (int j = b0 + l; j < b1; j += 64) {
        float v = esrc[csr_src[j]] + ed;
        v = (v >= 0.f) ? v : 0.2f * v;
        m = fmaxf(m, v);
    }
    #pragma unroll
    for (int off = 32; off; off >>= 1) m = fmaxf(m, __shfl_xor(m, off));
    float sum = 0.f;
    for (int j = b0 + l; j < b1; j += 64) {
        float v = esrc[csr_src[j]] + ed;
        v = (v >= 0.f) ? v : 0.2f * v;
        float ex = expf(v - m);
        alpha[j] = ex; sum += ex;
    }
    #pragma unroll
    for (int off = 32; off; off >>= 1) sum += __shfl_xor(sum, off);
    float inv = 1.f / sum;
    for (int j = b0 + l; j < b1; j += 64) alpha[j] *= inv;
}

// ---------------- small elementwise kernels ----------------
__global__ void concat_t_k(const float* __restrict__ x, const float* __restrict__ se,
                           float* __restrict__ t)
{
    long idx = (long)blockIdx.x * 256 + threadIdx.x;
    long total = (long)NND * CG;
    if (idx >= total) return;
    int r = (int)(idx / CG), c = (int)(idx % CG);
    t[idx] = (c < HID) ? x[(long)r * HID + c] : se[(long)r * SDD + (c - HID)];
}

__global__ void copy_x_xc_k(const float* __restrict__ x, float* __restrict__ xc)
{
    long idx = (long)blockIdx.x * 256 + threadIdx.x;
    long total = (long)NND * HID;
    if (idx >= total) return;
    int r = (int)(idx / HID), c = (int)(idx % HID);
    xc[(long)r * 8192 + c] = x[idx];
}

__global__ void add_k(float* __restrict__ a, const float* __restrict__ b, long total)
{
    long idx = (long)blockIdx.x * 256 + threadIdx.x;
    if (idx >= total) return;
    a[idx] += b[idx];
}

__global__ void avg3_k(const float* __restrict__ a, const float* __restrict__ b,
                       const float* __restrict__ c, float* __restrict__ o, long total)
{
    long idx = (long)blockIdx.x * 256 + threadIdx.x;
    if (idx >= total) return;
    o[idx] = (a[idx] + b[idx] + c[idx]) * (1.f / 3.f);
}

__global__ __launch_bounds__(256)
void gat_dots_k(const float* __restrict__ h, const float* __restrict__ asrc,
                const float* __restrict__ adst, float* __restrict__ esrc,
                float* __restrict__ edst)
{
    int n = blockIdx.x, tid = threadIdx.x;
    float s1 = 0.f, s2 = 0.f;
    for (int f = tid; f < HID; f += 256) {
        float v = h[(long)n * HID + f];
        s1 += v * asrc[f]; s2 += v * adst[f];
    }
    __shared__ float r1[256], r2[256];
    r1[tid] = s1; r2[tid] = s2; __syncthreads();
    for (int s = 128; s > 0; s >>= 1) {
        if (tid < s) { r1[tid] += r1[tid + s]; r2[tid] += r2[tid + s]; }
        __syncthreads();
    }
    if (tid == 0) { esrc[n] = r1[0]; edst[n] = r2[0]; }
}

__global__ void pair_idx_k(const int* __restrict__ eidx, const int* __restrict__ teid,
                           int* __restrict__ n0, int* __restrict__ n1)
{
    int p = blockIdx.x * 256 + threadIdx.x;
    if (p >= BP) return;
    int t = teid[p];
    n0[p] = eidx[t];
    n1[p] = eidx[EMN + t];
}

// ---------------- launch ----------------
static inline int cdiv(long a, int b) { return (int)((a + b - 1) / b); }

extern "C" void kernel_launch(void* const* d_in, const int* in_sizes, int n_in,
                              void* d_out, int out_size, void* d_ws, size_t ws_size,
                              hipStream_t stream)
{
    const float* x    = (const float*)d_in[0];
    const float* se   = (const float*)d_in[1];
    const int*   sev  = (const int*)  d_in[2];
    const int*   eidx = (const int*)  d_in[3];
    const int*   teid = (const int*)  d_in[4];
    const float* gpsW = (const float*)d_in[5];
    const float* gpsB = (const float*)d_in[6];
    const float* aiW  = (const float*)d_in[7];
    const float* aiB  = (const float*)d_in[8];
    const float* aoW  = (const float*)d_in[9];
    const float* aoB  = (const float*)d_in[10];
    const float* bn1g = (const float*)d_in[11];
    const float* bn1b = (const float*)d_in[12];
    const float* bn2g = (const float*)d_in[13];
    const float* bn2b = (const float*)d_in[14];
    const float* bn3g = (const float*)d_in[15];
    const float* bn3b = (const float*)d_in[16];
    const float* mW1  = (const float*)d_in[17];
    const float* mb1  = (const float*)d_in[18];
    const float* mW2  = (const float*)d_in[19];
    const float* mb2  = (const float*)d_in[20];
    const float* slW  = (const float*)d_in[21];
    const float* slB  = (const float*)d_in[22];
    const float* gatW = (const float*)d_in[23];
    const float* gatAs= (const float*)d_in[24];
    const float* gatAd= (const float*)d_in[25];
    const float* gatB = (const float*)d_in[26];
    const float* subW = (const float*)d_in[27];
    const float* subB = (const float*)d_in[28];
    const float* gcnW = (const float*)d_in[29];
    const float* gcnB = (const float*)d_in[30];
    const float* bnfg = (const float*)d_in[31];
    const float* bnfb = (const float*)d_in[32];
    const float* cW0 = (const float*)d_in[33]; const float* cb0 = (const float*)d_in[34];
    const float* cW1 = (const float*)d_in[35]; const float* cb1 = (const float*)d_in[36];
    const float* cW2 = (const float*)d_in[37]; const float* cb2 = (const float*)d_in[38];
    const float* cW3 = (const float*)d_in[39]; const float* cb3 = (const float*)d_in[40];
    const float* cW4 = (const float*)d_in[41]; const float* cb4 = (const float*)d_in[42];
    const float* cW5 = (const float*)d_in[43]; const float* cb5 = (const float*)d_in[44];
    float* out = (float*)d_out;
    float* w   = (float*)d_ws;

    // ---- workspace layout (floats), peak ~195 MiB ----
    const size_t o_xc  = 0;                          // 2048*8192 (persistent)
    const size_t region= (size_t)NND * 8192;
    const size_t o_t   = region;
    const size_t o_ha  = o_t  + (size_t)NND * CG;
    const size_t o_hb  = o_ha + (size_t)NND * CG;
    const size_t o_hc  = o_hb + (size_t)NND * CG;
    const size_t o_qkv = o_hc + (size_t)NND * CG;    // 2048*3132
    const size_t o_sc  = o_qkv+ (size_t)NND * 3*CG;  // 4*2048*2048 scores
    const size_t o_mid = o_sc;                       // alias: 2048*2088 (MLP mid)
    const size_t o_u0  = o_sc + (size_t)NND * 2*CG;  // alias: 5 x 2048*1024
    const size_t o_u1  = o_u0 + (size_t)NND * HID;
    const size_t o_u2  = o_u1 + (size_t)NND * HID;
    const size_t o_u3  = o_u2 + (size_t)NND * HID;
    const size_t o_u4  = o_u3 + (size_t)NND * HID;
    const size_t o_sm  = o_sc + (size_t)NHEAD * NND * NND;   // past score region
    const size_t o_div = o_sm;
    const size_t o_dli = o_div + NND;
    const size_t o_es  = o_dli + NND;
    const size_t o_ed  = o_es + NND;
    const size_t o_al  = o_ed + NND;                 // ESL edge alphas
    const size_t o_int = o_al + ESL;
    int* ideg = (int*)(w + o_int);
    int* irow = ideg + NND;
    int* icur = irow + NND + 1;
    int* icsr = icur + NND;
    int* pn0  = icsr + ESL;
    int* pn1  = pn0 + BP;
    const size_t o_c1  = region;                     // 4096*4096
    const size_t o_c2  = region + (size_t)BP * 4096; // 4096*2048

    const float scale = 1.f / sqrtf((float)DH);

    copy_x_xc_k<<<cdiv((long)NND * HID, 256), 256, 0, stream>>>(x, w + o_xc);

    for (int i = 0; i < KC; ++i) {
        const int* srcp = sev + (long)i * 2 * EE;
        const int* dstp = srcp + EE;
        float* t  = w + o_t;
        float* hA = w + o_ha;
        float* hB = w + o_hb;
        float* hC = w + o_hc;

        concat_t_k<<<cdiv((long)NND * CG, 256), 256, 0, stream>>>(x, se + (long)i * NND * SDD, t);

        // ---- CSR build ----
        hipMemsetAsync(ideg, 0, NND * sizeof(int), stream);
        count_deg_k<<<cdiv(ESL, 256), 256, 0, stream>>>(dstp, ideg);
        scan_k<<<1, 256, 0, stream>>>(ideg, irow, icur, w + o_div, w + o_dli);
        scatter_k<<<cdiv(ESL, 256), 256, 0, stream>>>(srcp, dstp, icur, icsr);

        // ---- GCN1 ----
        gemm(stream, t, CG, 0, gpsW + (long)i * CG * CG, CG, 0, hA, CG, 0,
             NND, CG, CG, nullptr, false, false, 1);
        gather_k<5, 1><<<NND, 256, 0, stream>>>(hA, irow, icsr, w + o_div, nullptr,
                                                gpsB + (long)i * CG, nullptr, hB, CG);
        bn_k<<<cdiv(CG, 32), 256, 0, stream>>>(hB, t, hB, bn1g + (long)i * CG, bn1b + (long)i * CG, NND, CG, CG);

        // ---- MHA ----
        gemm(stream, t, CG, 0, aiW + (long)i * 3 * CG * CG, CG, 0, w + o_qkv, 3 * CG, 0,
             NND, 3 * CG, CG, aiB + (long)i * 3 * CG, true, false, 1);
        gemm(stream, w + o_qkv, 3 * CG, DH, w + o_qkv + CG, 3 * CG, DH,
             w + o_sc, NND, (long)NND * NND, NND, NND, DH, nullptr, true, false, NHEAD);
        softmax_rows_k<<<NHEAD * NND, 256, 0, stream>>>(w + o_sc, NND, scale);
        gemm(stream, w + o_sc, NND, (long)NND * NND, w + o_qkv + 2 * CG, 3 * CG, DH,
             hA, CG, DH, NND, DH, NND, nullptr, false, false, NHEAD);
        gemm(stream, hA, CG, 0, aoW + (long)i * CG * CG, CG, 0, hC, CG, 0,
             NND, CG, CG, aoB + (long)i * CG, true, false, 1);
        bn_k<<<cdiv(CG, 32), 256, 0, stream>>>(hC, t, hC, bn2g + (long)i * CG, bn2b + (long)i * CG, NND, CG, CG);

        add_k<<<cdiv((long)NND * CG, 256), 256, 0, stream>>>(hB, hC, (long)NND * CG);

        // ---- MLP + bn3 ----
        gemm(stream, hB, CG, 0, mW1 + (long)i * CG * 2 * CG, 2 * CG, 0, w + o_mid, 2 * CG, 0,
             NND, 2 * CG, CG, mb1 + (long)i * 2 * CG, false, true, 1);
        gemm(stream, w + o_mid, 2 * CG, 0, mW2 + (long)i * 2 * CG * CG, CG, 0, hC, CG, 0,
             NND, CG, 2 * CG, mb2 + (long)i * CG, false, false, 1);
        bn_k<<<cdiv(CG, 32), 256, 0, stream>>>(hC, hB, hB, bn3g + (long)i * CG, bn3b + (long)i * CG, NND, CG, CG);

        // ---- se_lin ----
        gemm(stream, hB, CG, 0, slW + (long)i * CG * HID, HID, 0, w + o_u0, HID, 0,
             NND, HID, CG, slB + (long)i * HID, false, false, 1);

        // ---- GAT ----
        gemm(stream, w + o_u0, HID, 0, gatW + (long)i * HID * HID, HID, 0, w + o_u1, HID, 0,
             NND, HID, HID, nullptr, false, false, 1);
        gat_dots_k<<<NND, 256, 0, stream>>>(w + o_u1, gatAs + (long)i * HID, gatAd + (long)i * HID,
                                            w + o_es, w + o_ed);
        gat_alpha_k<<<NND, 64, 0, stream>>>(w + o_es, w + o_ed, irow, icsr, w + o_al);
        gather_k<4, 2><<<NND, 256, 0, stream>>>(w + o_u1, irow, icsr, nullptr, w + o_al,
                                                gatB + (long)i * HID, nullptr, w + o_u2, HID);

        // ---- h1 / h2 mean aggregations ----
        gather_k<4, 0><<<NND, 256, 0, stream>>>(w + o_u2, irow, icsr, nullptr, nullptr,
                                                nullptr, w + o_dli, w + o_u3, HID);
        gather_k<4, 0><<<NND, 256, 0, stream>>>(w + o_u3, irow, icsr, nullptr, nullptr,
                                                nullptr, w + o_dli, w + o_u4, HID);

        avg3_k<<<cdiv((long)NND * HID, 256), 256, 0, stream>>>(w + o_u2, w + o_u3, w + o_u4, w + o_u0, (long)NND * HID);
        gemm(stream, w + o_u0, HID, 0, subW + (long)i * HID * HID, HID, 0, w + o_u1, HID, 0,
             NND, HID, HID, subB + (long)i * HID, false, true, 1);

        // ---- GCN2 ----
        gemm(stream, w + o_u2, HID, 0, gcnW + (long)i * HID * HID, HID, 0, w + o_u4, HID, 0,
             NND, HID, HID, nullptr, false, false, 1);
        gather_k<4, 1><<<NND, 256, 0, stream>>>(w + o_u4, irow, icsr, w + o_div, nullptr,
                                                gcnB + (long)i * HID, nullptr, w + o_u3, HID);

        bn_k<<<cdiv(HID, 32), 256, 0, stream>>>(w + o_u3, w + o_u1, w + o_xc + (size_t)HID * (i + 1),
                                                bnfg + (long)i * HID, bnfb + (long)i * HID, NND, HID, 8192);
    }

    // ---- classifier ----
    pair_idx_k<<<cdiv(BP, 256), 256, 0, stream>>>(eidx, teid, pn0, pn1);
    {
        dim3 g((4096 + 127) / 128, BP / 128, 1), blk(256);
        gemm_mfma_k<false, false, true, 3><<<g, blk, 0, stream>>>(
            w + o_xc, 8192, 0, cW0, 4096, 0, w + o_c1, 4096, 0,
            BP, 4096, 8192, cb0, pn0, pn1);
    }
    gemm(stream, w + o_c1, 4096, 0, cW1, 2048, 0, w + o_c2, 2048, 0, BP, 2048, 4096, cb1, false, false, 1);
    gemm(stream, w + o_c2, 2048, 0, cW2, 1024, 0, w + o_c1, 1024, 0, BP, 1024, 2048, cb2, false, false, 1);
    gemm(stream, w + o_c1, 1024, 0, cW3,  512, 0, w + o_c2,  512, 0, BP,  512, 1024, cb3, false, false, 1);
    gemm(stream, w + o_c2,  512, 0, cW4,  256, 0, w + o_c1,  256, 0, BP,  256,  512, cb4, false, false, 1);
    gemm(stream, w + o_c1,  256, 0, cW5,    7, 0, out,         7, 0, BP,    7,  256, cb5, false, false, 1);
}